// Round 2
// baseline (931.872 us; speedup 1.0000x reference)
//
#include <hip/hip_runtime.h>
#include <cstdint>
#include <cstddef>

typedef unsigned short ushort;
typedef __attribute__((ext_vector_type(8))) short short8;
typedef __attribute__((ext_vector_type(8))) unsigned short ushort8;
typedef __attribute__((ext_vector_type(4))) float float4v;

#define DM    2048
#define INNERC 4096
#define LSEQ  4096
#define NBATCH 2
#define MROWS 8192      // NBATCH*LSEQ
#define NHH   64
#define HDD   64
#define NCHUNK 32
#define CHLEN  128

__device__ __forceinline__ float bf2f(ushort u) {
    return __uint_as_float(((unsigned int)u) << 16);
}
__device__ __forceinline__ ushort f2bf(float f) {
    unsigned int u = __float_as_uint(f);
    unsigned int r = u + 0x7FFFu + ((u >> 16) & 1u);
    return (ushort)(r >> 16);
}

// ---------------- diagnostic: report ws MiB via absmax if guard trips ------
__global__ void diag_kernel(float* __restrict__ out, float val) {
    if (threadIdx.x == 0 && blockIdx.x == 0) out[0] = val;
}

// ---------------- f32 -> bf16 cast ----------------
__global__ __launch_bounds__(256) void cast_bf16_kernel(
    const float* __restrict__ in, ushort* __restrict__ out, int n) {
    const int i = (blockIdx.x * 256 + threadIdx.x) * 8;
    if (i + 8 > n) return;
    const float4v a = *(const float4v*)(in + i);
    const float4v b = *(const float4v*)(in + i + 4);
    ushort8 o;
    o[0] = f2bf(a[0]); o[1] = f2bf(a[1]); o[2] = f2bf(a[2]); o[3] = f2bf(a[3]);
    o[4] = f2bf(b[0]); o[5] = f2bf(b[1]); o[6] = f2bf(b[2]); o[7] = f2bf(b[3]);
    *(ushort8*)(out + i) = o;
}

// ---------------- bf16 bt-GEMM: Out(M,N) = A(M,K) * W(N,K)^T ----------------
// 128x128 tile, BK=64, 256 threads = 4 waves (each 64x64 quadrant).
// LDS: 16B chunks; physical slot c holds (row=c>>3, kg=(c&7)^(row&7)) (XOR
// swizzle: coalesced staging + <=2-way LDS bank aliasing on ds_read_b128).
// EPI: 0 = store bf16, 1 = sigmoid(acc)*Aux[off] -> bf16 (in-place ok),
//      2 = store f32.
template <int EPI>
__global__ __launch_bounds__(256, 2) void gemm_bt(
    const ushort* __restrict__ Ab, const ushort* __restrict__ Wb,
    void* __restrict__ Out, const ushort* __restrict__ Aux,
    int M, int N, int K) {
    __shared__ ushort As[128 * 64];
    __shared__ ushort Bs[128 * 64];
    const int tid  = threadIdx.x;
    const int lane = tid & 63;
    const int w    = tid >> 6;
    const int wm   = w >> 1, wn = w & 1;
    const int row0 = blockIdx.y * 128;
    const int col0 = blockIdx.x * 128;

    float4v acc[4][4];
#pragma unroll
    for (int i = 0; i < 4; i++)
#pragma unroll
        for (int j = 0; j < 4; j++) {
            float4v z = {0.f, 0.f, 0.f, 0.f};
            acc[i][j] = z;
        }

    ushort8 pA[4], pB[4];
#pragma unroll
    for (int t = 0; t < 4; t++) {
        const int c   = t * 256 + tid;
        const int row = c >> 3;
        const int kg  = (c & 7) ^ (row & 7);
        pA[t] = *(const ushort8*)(Ab + (size_t)(row0 + row) * K + kg * 8);
        pB[t] = *(const ushort8*)(Wb + (size_t)(col0 + row) * K + kg * 8);
    }

    for (int k0 = 0; k0 < K; k0 += 64) {
        __syncthreads();   // previous compute done before LDS overwrite
#pragma unroll
        for (int t = 0; t < 4; t++) {
            const int c = t * 256 + tid;
            *(ushort8*)&As[c * 8] = pA[t];
            *(ushort8*)&Bs[c * 8] = pB[t];
        }
        __syncthreads();
        if (k0 + 64 < K) {  // prefetch next K-step (overlaps with MFMA below)
#pragma unroll
            for (int t = 0; t < 4; t++) {
                const int c   = t * 256 + tid;
                const int row = c >> 3;
                const int kg  = (c & 7) ^ (row & 7);
                pA[t] = *(const ushort8*)(Ab + (size_t)(row0 + row) * K + (k0 + 64) + kg * 8);
                pB[t] = *(const ushort8*)(Wb + (size_t)(col0 + row) * K + (k0 + 64) + kg * 8);
            }
        }
#pragma unroll
        for (int half = 0; half < 2; half++) {
            const int kq = half * 4 + (lane >> 4);
            short8 af[4], bfr[4];
#pragma unroll
            for (int rm = 0; rm < 4; rm++) {
                const int row = wm * 64 + rm * 16 + (lane & 15);
                af[rm] = *(const short8*)&As[(row * 8 + (kq ^ (row & 7))) * 8];
            }
#pragma unroll
            for (int cn = 0; cn < 4; cn++) {
                const int col = wn * 64 + cn * 16 + (lane & 15);
                bfr[cn] = *(const short8*)&Bs[(col * 8 + (kq ^ (col & 7))) * 8];
            }
#pragma unroll
            for (int rm = 0; rm < 4; rm++)
#pragma unroll
                for (int cn = 0; cn < 4; cn++)
                    acc[rm][cn] = __builtin_amdgcn_mfma_f32_16x16x32_bf16(
                        af[rm], bfr[cn], acc[rm][cn], 0, 0, 0);
        }
    }

    // epilogue: C/D layout col = lane&15, row = (lane>>4)*4 + reg
#pragma unroll
    for (int rm = 0; rm < 4; rm++) {
#pragma unroll
        for (int cn = 0; cn < 4; cn++) {
            const int r0 = row0 + wm * 64 + rm * 16 + (lane >> 4) * 4;
            const int cc = col0 + wn * 64 + cn * 16 + (lane & 15);
#pragma unroll
            for (int rr = 0; rr < 4; rr++) {
                const float v   = acc[rm][cn][rr];
                const size_t off = (size_t)(r0 + rr) * N + cc;
                if (EPI == 0) {
                    ((ushort*)Out)[off] = f2bf(v);
                } else if (EPI == 1) {
                    const float g = 1.0f / (1.0f + __expf(-v));
                    ((ushort*)Out)[off] = f2bf(g * bf2f(Aux[off]));
                } else {
                    ((float*)Out)[off] = v;
                }
            }
        }
    }
}

// ---------------- depthwise causal conv (K=4) + SiLU ----------------
__global__ __launch_bounds__(256) void conv_silu_kernel(
    const ushort* __restrict__ proj, const float* __restrict__ cw,
    const float* __restrict__ cb, ushort* __restrict__ X) {
    const int blk = blockIdx.x;
    const int bl  = blk >> 1;
    const int l   = bl & (LSEQ - 1);
    const int c0  = (blk & 1) * 2048 + threadIdx.x * 8;
    const size_t base = (size_t)bl * INNERC + c0;
    float acc[8];
#pragma unroll
    for (int j = 0; j < 8; j++) acc[j] = cb[c0 + j];
#pragma unroll
    for (int k = 0; k < 4; k++) {
        const int dl = k - 3;
        if (l + dl >= 0) {
            const ushort8 v = *(const ushort8*)(proj + base + (ptrdiff_t)dl * INNERC);
#pragma unroll
            for (int j = 0; j < 8; j++) acc[j] += cw[(c0 + j) * 4 + k] * bf2f(v[j]);
        }
    }
    ushort8 o;
#pragma unroll
    for (int j = 0; j < 8; j++) {
        const float y = acc[j];
        o[j] = f2bf(y / (1.0f + __expf(-y)));   // silu
    }
    *(ushort8*)(X + base) = o;
}

// ---------------- dt = softplus(sum_p X*dt_w + dt_b) ----------------
__global__ __launch_bounds__(64) void dt_kernel(
    const ushort* __restrict__ X, const float* __restrict__ dtw,
    const float* __restrict__ dtb, float* __restrict__ dt) {
    const int bl = blockIdx.x;
    const int h  = threadIdx.x;
    const ushort* xp = X + (size_t)bl * INNERC + h * 64;
    const float*  wp = dtw + h * 64;
    float acc = 0.0f;
#pragma unroll
    for (int p0 = 0; p0 < 64; p0 += 8) {
        const ushort8 xv = *(const ushort8*)(xp + p0);
#pragma unroll
        for (int j = 0; j < 8; j++) acc += bf2f(xv[j]) * wp[p0 + j];
    }
    const float z = acc + dtb[h];
    dt[bl * 64 + h] = (z > 20.0f) ? z : __logf(1.0f + __expf(z));
}

// ---------------- chunked diagonal scan ----------------
__global__ __launch_bounds__(256) void scan_pass1(
    const ushort* __restrict__ X, const float* __restrict__ dt,
    const float* __restrict__ A_log, const float* __restrict__ Bv,
    float* __restrict__ sumP, float* __restrict__ sumS) {
    const int task = blockIdx.x * 4 + (threadIdx.x >> 6);
    const int p  = threadIdx.x & 63;
    const int ch = task & (NCHUNK - 1);
    const int bh = task >> 5;
    const int h  = bh & 63;
    const int b  = bh >> 6;
    const float Ac = -__expf(A_log[h * 64 + p]);
    const float Bc = Bv[h * 64 + p];
    float Pr = 1.0f, s = 0.0f;
    const int bl0 = b * LSEQ + ch * CHLEN;
#pragma unroll 4
    for (int i = 0; i < CHLEN; i++) {
        const int bl   = bl0 + i;
        const float dtv = dt[bl * 64 + h];
        const float x   = bf2f(X[(size_t)bl * INNERC + h * 64 + p]);
        const float a   = __expf(dtv * Ac);
        Pr *= a;
        s = a * s + dtv * Bc * x;
    }
    sumP[(size_t)task * 64 + p] = Pr;
    sumS[(size_t)task * 64 + p] = s;
}

__global__ __launch_bounds__(64) void scan_pass2(
    const float* __restrict__ sumP, const float* __restrict__ sumS,
    float* __restrict__ carry) {
    const int bh = blockIdx.x;
    const int p  = threadIdx.x;
    float c = 0.0f;
    for (int ch = 0; ch < NCHUNK; ch++) {
        const size_t idx = ((size_t)bh * NCHUNK + ch) * 64 + p;
        carry[idx] = c;
        c = sumP[idx] * c + sumS[idx];
    }
}

// pass3: recompute scan within chunk, write y = C*s + D*x (bf16) to Y.
__global__ __launch_bounds__(256) void scan_pass3(
    const ushort* __restrict__ X, const float* __restrict__ dt,
    const float* __restrict__ carry,
    const float* __restrict__ A_log, const float* __restrict__ Bv,
    const float* __restrict__ Cv, const float* __restrict__ Dv,
    ushort* __restrict__ Y) {
    const int task = blockIdx.x * 4 + (threadIdx.x >> 6);
    const int p  = threadIdx.x & 63;
    const int ch = task & (NCHUNK - 1);
    const int bh = task >> 5;
    const int h  = bh & 63;
    const int b  = bh >> 6;
    const float Ac = -__expf(A_log[h * 64 + p]);
    const float Bc = Bv[h * 64 + p];
    const float Cc = Cv[h * 64 + p];
    const float Dc = Dv[h * 64 + p];
    float s = carry[(size_t)task * 64 + p];
    const int bl0 = b * LSEQ + ch * CHLEN;
#pragma unroll 2
    for (int i = 0; i < CHLEN; i++) {
        const int bl = bl0 + i;
        const size_t xoff = (size_t)bl * INNERC + h * 64 + p;
        const float dtv = dt[bl * 64 + h];
        const float x   = bf2f(X[xoff]);
        const float a   = __expf(dtv * Ac);
        s = a * s + dtv * Bc * x;
        Y[xoff] = f2bf(Cc * s + Dc * x);
    }
}

// ---------------- workspace layout (bytes) ----------------
// X (bf16 8192x4096 = 67,108,864 B) lives in d_out (same byte size);
// final out-GEMM overwrites it with f32 results after X is dead.
#define OFF_PROJ  ((size_t)0)            // 67,108,864 : proj -> Y -> comb
#define OFF_HID   ((size_t)67108864)     // 33,554,432 : hidden bf16
#define OFF_WB    ((size_t)100663296)    // 16,777,216 : weight bf16 (reused 3x)
#define OFF_DT    ((size_t)117440512)    //  2,097,152
#define OFF_SUMP  ((size_t)119537664)    //  1,048,576
#define OFF_SUMS  ((size_t)120586240)    //  1,048,576
#define OFF_CARRY ((size_t)121634816)    //  1,048,576
#define WS_NEEDED ((size_t)122683392)    // = 117 MiB

extern "C" void kernel_launch(void* const* d_in, const int* in_sizes, int n_in,
                              void* d_out, int out_size, void* d_ws, size_t ws_size,
                              hipStream_t stream) {
    if (ws_size < WS_NEEDED) {
        // Signal actual ws size through absmax: d_out[0] = ws MiB.
        diag_kernel<<<1, 64, 0, stream>>>((float*)d_out, (float)(ws_size >> 20));
        return;
    }
    const float* hidden = (const float*)d_in[0];
    const float* w_in   = (const float*)d_in[1];
    const float* w_gate = (const float*)d_in[2];
    const float* w_out  = (const float*)d_in[3];
    const float* conv_w = (const float*)d_in[4];
    const float* conv_b = (const float*)d_in[5];
    const float* dt_w   = (const float*)d_in[6];
    const float* dt_b   = (const float*)d_in[7];
    const float* A_log  = (const float*)d_in[8];
    const float* Bv     = (const float*)d_in[9];
    const float* Cv     = (const float*)d_in[10];
    const float* Dv     = (const float*)d_in[11];

    char* ws = (char*)d_ws;
    ushort* projbuf = (ushort*)(ws + OFF_PROJ);   // proj, then Y, then comb
    ushort* hid16   = (ushort*)(ws + OFF_HID);
    ushort* wbuf    = (ushort*)(ws + OFF_WB);
    float*  dtf     = (float*)(ws + OFF_DT);
    float*  sumP    = (float*)(ws + OFF_SUMP);
    float*  sumS    = (float*)(ws + OFF_SUMS);
    float*  carry   = (float*)(ws + OFF_CARRY);
    ushort* x16     = (ushort*)d_out;             // X scratch inside d_out

    // hidden + in_proj weight casts
    cast_bf16_kernel<<<8192, 256, 0, stream>>>(hidden, hid16, MROWS * DM);
    cast_bf16_kernel<<<4096, 256, 0, stream>>>(w_in, wbuf, INNERC * DM);

    // in_proj GEMM -> proj (bf16)
    gemm_bt<0><<<dim3(INNERC / 128, MROWS / 128), 256, 0, stream>>>(
        hid16, wbuf, projbuf, nullptr, MROWS, INNERC, DM);

    // conv + silu -> X (in d_out), then dt
    conv_silu_kernel<<<MROWS * 2, 256, 0, stream>>>(projbuf, conv_w, conv_b, x16);
    dt_kernel<<<MROWS, 64, 0, stream>>>(x16, dt_w, dt_b, dtf);

    // chunked scan; pass3 writes y into projbuf (proj dead after conv)
    scan_pass1<<<(NBATCH * NHH * NCHUNK) / 4, 256, 0, stream>>>(
        x16, dtf, A_log, Bv, sumP, sumS);
    scan_pass2<<<NBATCH * NHH, 64, 0, stream>>>(sumP, sumS, carry);
    scan_pass3<<<(NBATCH * NHH * NCHUNK) / 4, 256, 0, stream>>>(
        x16, dtf, carry, A_log, Bv, Cv, Dv, projbuf);

    // gate GEMM with fused gating: comb = sigmoid(G) * Y, in-place in projbuf
    cast_bf16_kernel<<<4096, 256, 0, stream>>>(w_gate, wbuf, INNERC * DM);
    gemm_bt<1><<<dim3(INNERC / 128, MROWS / 128), 256, 0, stream>>>(
        hid16, wbuf, projbuf, projbuf, MROWS, INNERC, DM);

    // output projection (f32 out) — overwrites X scratch in d_out
    cast_bf16_kernel<<<4096, 256, 0, stream>>>(w_out, wbuf, DM * INNERC);
    gemm_bt<2><<<dim3(DM / 128, MROWS / 128), 256, 0, stream>>>(
        projbuf, wbuf, d_out, nullptr, MROWS, DM, INNERC);
}

// Round 3
// 698.680 us; speedup vs baseline: 1.3338x; 1.3338x over previous
//
#include <hip/hip_runtime.h>
#include <cstdint>
#include <cstddef>

typedef unsigned short ushort;
typedef __attribute__((ext_vector_type(8))) short short8;
typedef __attribute__((ext_vector_type(8))) unsigned short ushort8;
typedef __attribute__((ext_vector_type(4))) float float4v;

#define DM    2048
#define INNERC 4096
#define LSEQ  4096
#define NBATCH 2
#define MROWS 8192      // NBATCH*LSEQ
#define NHH   64
#define HDD   64
#define NCHUNK 32
#define CHLEN  128
#define CROWS 8         // conv rows per block

__device__ __forceinline__ float bf2f(ushort u) {
    return __uint_as_float(((unsigned int)u) << 16);
}
__device__ __forceinline__ ushort f2bf(float f) {
    unsigned int u = __float_as_uint(f);
    unsigned int r = u + 0x7FFFu + ((u >> 16) & 1u);
    return (ushort)(r >> 16);
}

// async global->LDS 16B copy (m97 pattern). LDS dest must be
// wave-uniform base + lane*16 — our chunk index c = t*256+tid is
// lane-linear, so &As[c*8] satisfies this.
__device__ __forceinline__ void async_cp16(const ushort* __restrict__ g, ushort* l) {
    __builtin_amdgcn_global_load_lds(
        (const __attribute__((address_space(1))) unsigned int*)g,
        (__attribute__((address_space(3))) unsigned int*)l,
        16, 0, 0);
}

// ---------------- diagnostic: report ws MiB via absmax if guard trips ------
__global__ void diag_kernel(float* __restrict__ out, float val) {
    if (threadIdx.x == 0 && blockIdx.x == 0) out[0] = val;
}

// ---------------- f32 -> bf16 cast ----------------
__global__ __launch_bounds__(256) void cast_bf16_kernel(
    const float* __restrict__ in, ushort* __restrict__ out, int n) {
    const int i = (blockIdx.x * 256 + threadIdx.x) * 8;
    if (i + 8 > n) return;
    const float4v a = *(const float4v*)(in + i);
    const float4v b = *(const float4v*)(in + i + 4);
    ushort8 o;
    o[0] = f2bf(a[0]); o[1] = f2bf(a[1]); o[2] = f2bf(a[2]); o[3] = f2bf(a[3]);
    o[4] = f2bf(b[0]); o[5] = f2bf(b[1]); o[6] = f2bf(b[2]); o[7] = f2bf(b[3]);
    *(ushort8*)(out + i) = o;
}

// ---------------- bf16 bt-GEMM: Out(M,N) = A(M,K) * W(N,K)^T ----------------
// 128x128 tile, BK=64, 256 threads = 4 waves (each 64x64 quadrant).
// LDS: 16B chunks; physical slot c holds (row=c>>3, kg=(c&7)^(row&7)) (XOR
// swizzle: coalesced staging + <=2-way LDS bank aliasing on ds_read_b128).
// Staging via global_load_lds width=16 (m97 structure).
// EPI: 0 = store bf16, 1 = sigmoid(acc)*Aux[off] -> bf16 (in-place ok),
//      2 = store f32.
template <int EPI>
__global__ __launch_bounds__(256, 2) void gemm_bt(
    const ushort* __restrict__ Ab, const ushort* __restrict__ Wb,
    void* __restrict__ Out, const ushort* __restrict__ Aux,
    int M, int N, int K) {
    __shared__ ushort As[128 * 64];
    __shared__ ushort Bs[128 * 64];
    const int tid  = threadIdx.x;
    const int lane = tid & 63;
    const int w    = tid >> 6;
    const int wm   = w >> 1, wn = w & 1;
    const int row0 = blockIdx.y * 128;
    const int col0 = blockIdx.x * 128;

    float4v acc[4][4];
#pragma unroll
    for (int i = 0; i < 4; i++)
#pragma unroll
        for (int j = 0; j < 4; j++) {
            float4v z = {0.f, 0.f, 0.f, 0.f};
            acc[i][j] = z;
        }

    for (int k0 = 0; k0 < K; k0 += 64) {
        __syncthreads();   // previous compute done before LDS overwrite
#pragma unroll
        for (int t = 0; t < 4; t++) {
            const int c   = t * 256 + tid;
            const int row = c >> 3;
            const int kg  = (c & 7) ^ (row & 7);
            async_cp16(Ab + (size_t)(row0 + row) * K + k0 + kg * 8, &As[c * 8]);
            async_cp16(Wb + (size_t)(col0 + row) * K + k0 + kg * 8, &Bs[c * 8]);
        }
        __syncthreads();   // drains vmcnt(0): staged data visible
#pragma unroll
        for (int half = 0; half < 2; half++) {
            const int kq = half * 4 + (lane >> 4);
            short8 af[4], bfr[4];
#pragma unroll
            for (int rm = 0; rm < 4; rm++) {
                const int row = wm * 64 + rm * 16 + (lane & 15);
                af[rm] = *(const short8*)&As[(row * 8 + (kq ^ (row & 7))) * 8];
            }
#pragma unroll
            for (int cn = 0; cn < 4; cn++) {
                const int col = wn * 64 + cn * 16 + (lane & 15);
                bfr[cn] = *(const short8*)&Bs[(col * 8 + (kq ^ (col & 7))) * 8];
            }
#pragma unroll
            for (int rm = 0; rm < 4; rm++)
#pragma unroll
                for (int cn = 0; cn < 4; cn++)
                    acc[rm][cn] = __builtin_amdgcn_mfma_f32_16x16x32_bf16(
                        af[rm], bfr[cn], acc[rm][cn], 0, 0, 0);
        }
    }

    // epilogue: C/D layout col = lane&15, row = (lane>>4)*4 + reg
#pragma unroll
    for (int rm = 0; rm < 4; rm++) {
#pragma unroll
        for (int cn = 0; cn < 4; cn++) {
            const int r0 = row0 + wm * 64 + rm * 16 + (lane >> 4) * 4;
            const int cc = col0 + wn * 64 + cn * 16 + (lane & 15);
#pragma unroll
            for (int rr = 0; rr < 4; rr++) {
                const float v   = acc[rm][cn][rr];
                const size_t off = (size_t)(r0 + rr) * N + cc;
                if (EPI == 0) {
                    ((ushort*)Out)[off] = f2bf(v);
                } else if (EPI == 1) {
                    const float g = 1.0f / (1.0f + __expf(-v));
                    ((ushort*)Out)[off] = f2bf(g * bf2f(Aux[off]));
                } else {
                    ((float*)Out)[off] = v;
                }
            }
        }
    }
}

// ---------------- depthwise causal conv (K=4) + SiLU ----------------
// Tiled: each block does CROWS=8 consecutive rows x 2048 channels.
// Weights loaded ONCE per block as contiguous 128B/lane (8 x float4),
// then a 4-row register sliding window — removes the per-row scattered
// weight loads that made round-2's conv TA-latency-bound (247us).
__global__ __launch_bounds__(256) void conv_silu_kernel(
    const ushort* __restrict__ proj, const float* __restrict__ cw,
    const float* __restrict__ cb, ushort* __restrict__ X) {
    const int blk  = blockIdx.x;          // 2048 blocks
    const int half = blk & 1;
    const int tile = blk >> 1;            // 1024 tiles of 8 rows
    const int bl0  = tile * CROWS;
    const bool atStart = ((bl0 & (LSEQ - 1)) == 0);
    const int c0 = half * 2048 + threadIdx.x * 8;

    float4v w[8];                         // w[j][k] = weight(channel c0+j, tap k)
    const float4v* wp4 = (const float4v*)(cw + (size_t)c0 * 4);
#pragma unroll
    for (int t = 0; t < 8; t++) w[t] = wp4[t];
    float bias[8];
    const float4v b0 = *(const float4v*)(cb + c0);
    const float4v b1 = *(const float4v*)(cb + c0 + 4);
#pragma unroll
    for (int t = 0; t < 4; t++) { bias[t] = b0[t]; bias[t + 4] = b1[t]; }

    const size_t base = (size_t)bl0 * INNERC + c0;
    ushort8 w0, w1, w2;
    const ushort8 zz = {0, 0, 0, 0, 0, 0, 0, 0};
    if (atStart) {
        w0 = zz; w1 = zz; w2 = zz;
    } else {
        w0 = *(const ushort8*)(proj + base - 3 * (size_t)INNERC);
        w1 = *(const ushort8*)(proj + base - 2 * (size_t)INNERC);
        w2 = *(const ushort8*)(proj + base - 1 * (size_t)INNERC);
    }
#pragma unroll
    for (int r = 0; r < CROWS; r++) {
        const ushort8 cur = *(const ushort8*)(proj + base + (size_t)r * INNERC);
        ushort8 o;
#pragma unroll
        for (int j = 0; j < 8; j++) {
            const float acc = bias[j]
                + w[j][0] * bf2f(w0[j]) + w[j][1] * bf2f(w1[j])
                + w[j][2] * bf2f(w2[j]) + w[j][3] * bf2f(cur[j]);
            o[j] = f2bf(acc / (1.0f + __expf(-acc)));   // silu
        }
        *(ushort8*)(X + base + (size_t)r * INNERC) = o;
        w0 = w1; w1 = w2; w2 = cur;
    }
}

// ---------------- dt = softplus(sum_p X*dt_w + dt_b) ----------------
__global__ __launch_bounds__(64) void dt_kernel(
    const ushort* __restrict__ X, const float* __restrict__ dtw,
    const float* __restrict__ dtb, float* __restrict__ dt) {
    const int bl = blockIdx.x;
    const int h  = threadIdx.x;
    const ushort* xp = X + (size_t)bl * INNERC + h * 64;
    const float*  wp = dtw + h * 64;
    float acc = 0.0f;
#pragma unroll
    for (int p0 = 0; p0 < 64; p0 += 8) {
        const ushort8 xv = *(const ushort8*)(xp + p0);
#pragma unroll
        for (int j = 0; j < 8; j++) acc += bf2f(xv[j]) * wp[p0 + j];
    }
    const float z = acc + dtb[h];
    dt[bl * 64 + h] = (z > 20.0f) ? z : __logf(1.0f + __expf(z));
}

// ---------------- chunked diagonal scan ----------------
__global__ __launch_bounds__(256) void scan_pass1(
    const ushort* __restrict__ X, const float* __restrict__ dt,
    const float* __restrict__ A_log, const float* __restrict__ Bv,
    float* __restrict__ sumP, float* __restrict__ sumS) {
    const int task = blockIdx.x * 4 + (threadIdx.x >> 6);
    const int p  = threadIdx.x & 63;
    const int ch = task & (NCHUNK - 1);
    const int bh = task >> 5;
    const int h  = bh & 63;
    const int b  = bh >> 6;
    const float Ac = -__expf(A_log[h * 64 + p]);
    const float Bc = Bv[h * 64 + p];
    float Pr = 1.0f, s = 0.0f;
    const int bl0 = b * LSEQ + ch * CHLEN;
#pragma unroll 4
    for (int i = 0; i < CHLEN; i++) {
        const int bl   = bl0 + i;
        const float dtv = dt[bl * 64 + h];
        const float x   = bf2f(X[(size_t)bl * INNERC + h * 64 + p]);
        const float a   = __expf(dtv * Ac);
        Pr *= a;
        s = a * s + dtv * Bc * x;
    }
    sumP[(size_t)task * 64 + p] = Pr;
    sumS[(size_t)task * 64 + p] = s;
}

__global__ __launch_bounds__(64) void scan_pass2(
    const float* __restrict__ sumP, const float* __restrict__ sumS,
    float* __restrict__ carry) {
    const int bh = blockIdx.x;
    const int p  = threadIdx.x;
    float c = 0.0f;
    for (int ch = 0; ch < NCHUNK; ch++) {
        const size_t idx = ((size_t)bh * NCHUNK + ch) * 64 + p;
        carry[idx] = c;
        c = sumP[idx] * c + sumS[idx];
    }
}

// pass3: recompute scan within chunk, write y = C*s + D*x (bf16) to Y.
__global__ __launch_bounds__(256) void scan_pass3(
    const ushort* __restrict__ X, const float* __restrict__ dt,
    const float* __restrict__ carry,
    const float* __restrict__ A_log, const float* __restrict__ Bv,
    const float* __restrict__ Cv, const float* __restrict__ Dv,
    ushort* __restrict__ Y) {
    const int task = blockIdx.x * 4 + (threadIdx.x >> 6);
    const int p  = threadIdx.x & 63;
    const int ch = task & (NCHUNK - 1);
    const int bh = task >> 5;
    const int h  = bh & 63;
    const int b  = bh >> 6;
    const float Ac = -__expf(A_log[h * 64 + p]);
    const float Bc = Bv[h * 64 + p];
    const float Cc = Cv[h * 64 + p];
    const float Dc = Dv[h * 64 + p];
    float s = carry[(size_t)task * 64 + p];
    const int bl0 = b * LSEQ + ch * CHLEN;
#pragma unroll 2
    for (int i = 0; i < CHLEN; i++) {
        const int bl = bl0 + i;
        const size_t xoff = (size_t)bl * INNERC + h * 64 + p;
        const float dtv = dt[bl * 64 + h];
        const float x   = bf2f(X[xoff]);
        const float a   = __expf(dtv * Ac);
        s = a * s + dtv * Bc * x;
        Y[xoff] = f2bf(Cc * s + Dc * x);
    }
}

// ---------------- workspace layout (bytes) ----------------
// X (bf16 8192x4096 = 67,108,864 B) lives in d_out (same byte size);
// final out-GEMM overwrites it with f32 results after X is dead.
#define OFF_PROJ  ((size_t)0)            // 67,108,864 : proj -> Y -> comb
#define OFF_HID   ((size_t)67108864)     // 33,554,432 : hidden bf16
#define OFF_WB    ((size_t)100663296)    // 16,777,216 : weight bf16 (reused 3x)
#define OFF_DT    ((size_t)117440512)    //  2,097,152
#define OFF_SUMP  ((size_t)119537664)    //  1,048,576
#define OFF_SUMS  ((size_t)120586240)    //  1,048,576
#define OFF_CARRY ((size_t)121634816)    //  1,048,576
#define WS_NEEDED ((size_t)122683392)    // = 117 MiB

extern "C" void kernel_launch(void* const* d_in, const int* in_sizes, int n_in,
                              void* d_out, int out_size, void* d_ws, size_t ws_size,
                              hipStream_t stream) {
    if (ws_size < WS_NEEDED) {
        // Signal actual ws size through absmax: d_out[0] = ws MiB.
        diag_kernel<<<1, 64, 0, stream>>>((float*)d_out, (float)(ws_size >> 20));
        return;
    }
    const float* hidden = (const float*)d_in[0];
    const float* w_in   = (const float*)d_in[1];
    const float* w_gate = (const float*)d_in[2];
    const float* w_out  = (const float*)d_in[3];
    const float* conv_w = (const float*)d_in[4];
    const float* conv_b = (const float*)d_in[5];
    const float* dt_w   = (const float*)d_in[6];
    const float* dt_b   = (const float*)d_in[7];
    const float* A_log  = (const float*)d_in[8];
    const float* Bv     = (const float*)d_in[9];
    const float* Cv     = (const float*)d_in[10];
    const float* Dv     = (const float*)d_in[11];

    char* ws = (char*)d_ws;
    ushort* projbuf = (ushort*)(ws + OFF_PROJ);   // proj, then Y, then comb
    ushort* hid16   = (ushort*)(ws + OFF_HID);
    ushort* wbuf    = (ushort*)(ws + OFF_WB);
    float*  dtf     = (float*)(ws + OFF_DT);
    float*  sumP    = (float*)(ws + OFF_SUMP);
    float*  sumS    = (float*)(ws + OFF_SUMS);
    float*  carry   = (float*)(ws + OFF_CARRY);
    ushort* x16     = (ushort*)d_out;             // X scratch inside d_out

    // hidden + in_proj weight casts
    cast_bf16_kernel<<<8192, 256, 0, stream>>>(hidden, hid16, MROWS * DM);
    cast_bf16_kernel<<<4096, 256, 0, stream>>>(w_in, wbuf, INNERC * DM);

    // in_proj GEMM -> proj (bf16)
    gemm_bt<0><<<dim3(INNERC / 128, MROWS / 128), 256, 0, stream>>>(
        hid16, wbuf, projbuf, nullptr, MROWS, INNERC, DM);

    // conv + silu -> X (in d_out), then dt
    conv_silu_kernel<<<(MROWS / CROWS) * 2, 256, 0, stream>>>(projbuf, conv_w, conv_b, x16);
    dt_kernel<<<MROWS, 64, 0, stream>>>(x16, dt_w, dt_b, dtf);

    // chunked scan; pass3 writes y into projbuf (proj dead after conv)
    scan_pass1<<<(NBATCH * NHH * NCHUNK) / 4, 256, 0, stream>>>(
        x16, dtf, A_log, Bv, sumP, sumS);
    scan_pass2<<<NBATCH * NHH, 64, 0, stream>>>(sumP, sumS, carry);
    scan_pass3<<<(NBATCH * NHH * NCHUNK) / 4, 256, 0, stream>>>(
        x16, dtf, carry, A_log, Bv, Cv, Dv, projbuf);

    // gate GEMM with fused gating: comb = sigmoid(G) * Y, in-place in projbuf
    cast_bf16_kernel<<<4096, 256, 0, stream>>>(w_gate, wbuf, INNERC * DM);
    gemm_bt<1><<<dim3(INNERC / 128, MROWS / 128), 256, 0, stream>>>(
        hid16, wbuf, projbuf, projbuf, MROWS, INNERC, DM);

    // output projection (f32 out) — overwrites X scratch in d_out
    cast_bf16_kernel<<<4096, 256, 0, stream>>>(w_out, wbuf, DM * INNERC);
    gemm_bt<2><<<dim3(DM / 128, MROWS / 128), 256, 0, stream>>>(
        projbuf, wbuf, d_out, nullptr, MROWS, DM, INNERC);
}